// Round 1
// baseline (567.862 us; speedup 1.0000x reference)
//
#include <hip/hip_runtime.h>

#define EPS 1e-4f
#define BB 64
#define NN 1024   // N1 == N2 == 1024 (static per reference)

typedef _Float16 f16x8 __attribute__((ext_vector_type(8)));
typedef _Float16 f16x4 __attribute__((ext_vector_type(4)));

// ---------------------------------------------------------------------------
// K1: compress s -> A (fp16, +EPS, zero-padded beyond nc) and first column
// sums (c1 partials). grid (16, B) -- 16 chunks x 64 rows; block 256.
// Thread t owns cols [4t, 4t+4). Rows >= nr are skipped (A garbage there is
// never read). partial layout: [chunk][b][1024].
// ---------------------------------------------------------------------------
__global__ __launch_bounds__(256) void compress_colsum_k(
    const float* __restrict__ s, _Float16* __restrict__ A,
    const int* __restrict__ nrows, const int* __restrict__ ncols,
    float* __restrict__ partial)
{
    int chunk = blockIdx.x;
    int b = blockIdx.y;
    int nr = nrows[b], nc = ncols[b];
    int t = threadIdx.x;
    int j = t << 2;
    int i0 = chunk << 6;
    int i1 = min(i0 + 64, nr);
    const float* sb = s + ((size_t)b << 20) + j;
    _Float16* Ab = A + ((size_t)b << 20) + j;
    float a0 = 0.f, a1 = 0.f, a2 = 0.f, a3 = 0.f;
    if (j < nc) {
        for (int i = i0; i < i1; ++i) {
            float4 v = *(const float4*)(sb + ((size_t)i << 10));
            float m0 = (j + 0 < nc) ? v.x + EPS : 0.f;
            float m1 = (j + 1 < nc) ? v.y + EPS : 0.f;
            float m2 = (j + 2 < nc) ? v.z + EPS : 0.f;
            float m3 = (j + 3 < nc) ? v.w + EPS : 0.f;
            f16x4 h;
            h[0] = (_Float16)m0; h[1] = (_Float16)m1;
            h[2] = (_Float16)m2; h[3] = (_Float16)m3;
            // accumulate the ROUNDED values so c1 is exactly consistent with A
            a0 += (float)h[0]; a1 += (float)h[1];
            a2 += (float)h[2]; a3 += (float)h[3];
            *(f16x4*)(Ab + ((size_t)i << 10)) = h;
        }
    } else {
        f16x4 z = {};
        for (int i = i0; i < i1; ++i)
            *(f16x4*)(Ab + ((size_t)i << 10)) = z;
    }
    *(float4*)(partial + (((size_t)((chunk << 6) + b)) << 10) + j) =
        make_float4(a0, a1, a2, a3);
}

// ---------------------------------------------------------------------------
// K2: fused (col-normalize -> row-normalize -> next column-sum partial).
// grid (16, B), block 256. Stage c = 1/colsum (masked) into LDS from the
// 16-chunk partials; each wave owns rows (chunk*64 + w) mod 4, processing
// TWO rows per iteration (interleaved butterflies) so the shuffle latency of
// one row hides under the other. Dot products are split into 4 parallel
// FMA chains (strict-FP-legal reassociation done by hand).
// ---------------------------------------------------------------------------
__global__ __launch_bounds__(256) void pair_k(
    const _Float16* __restrict__ A, const float* __restrict__ pin,
    const int* __restrict__ nrows, const int* __restrict__ ncols,
    float* __restrict__ pout)
{
    __shared__ float cs[NN];        // 4 KB
    __shared__ float mg[4][NN];     // 16 KB
    int chunk = blockIdx.x, b = blockIdx.y;
    int nr = nrows[b], nc = ncols[b];
    int t = threadIdx.x;
    {
        int j = t << 2;
        const float* pb = pin + ((size_t)b << 10) + j;
        float4 u = make_float4(0.f, 0.f, 0.f, 0.f);
#pragma unroll
        for (int k = 0; k < 16; ++k) {          // chunk stride = 64*1024 = 1<<16
            float4 p = *(const float4*)(pb + ((size_t)k << 16));
            u.x += p.x; u.y += p.y; u.z += p.z; u.w += p.w;
        }
        cs[j + 0] = (j + 0 < nc) ? 1.0f / u.x : 0.f;
        cs[j + 1] = (j + 1 < nc) ? 1.0f / u.y : 0.f;
        cs[j + 2] = (j + 2 < nc) ? 1.0f / u.z : 0.f;
        cs[j + 3] = (j + 3 < nc) ? 1.0f / u.w : 0.f;
    }
    __syncthreads();

    int w = t >> 6, lane = t & 63;
    int col0 = lane << 3;                 // cols [col0, col0+8) and [512+col0, ...)
    float4 c0a = *(const float4*)&cs[col0];
    float4 c0b = *(const float4*)&cs[col0 + 4];
    float4 c1a = *(const float4*)&cs[512 + col0];
    float4 c1b = *(const float4*)&cs[512 + col0 + 4];
    bool do1 = (512 + col0) < nc;         // nc >= 512 so first half always live

    float acc0[8] = {0.f, 0.f, 0.f, 0.f, 0.f, 0.f, 0.f, 0.f};
    float acc1[8] = {0.f, 0.f, 0.f, 0.f, 0.f, 0.f, 0.f, 0.f};
    const _Float16* Ab = A + ((size_t)b << 20);
    int i0 = chunk << 6;
    int iend = min(i0 + 64, nr);
    for (int i = i0 + w; i < iend; i += 8) {
        int ib = i + 4;
        bool hasB = ib < iend;
        const _Float16* rA = Ab + ((size_t)i << 10);
        const _Float16* rB = Ab + ((size_t)(hasB ? ib : i) << 10); // safe dup
        f16x8 qa0 = *(const f16x8*)(rA + col0);
        f16x8 qb0 = *(const f16x8*)(rB + col0);
        f16x8 qa1 = {}; f16x8 qb1 = {};
        if (do1) {
            qa1 = *(const f16x8*)(rA + 512 + col0);
            qb1 = *(const f16x8*)(rB + 512 + col0);
        }
        float fa0[8], fa1[8], fb0[8], fb1[8];
#pragma unroll
        for (int k = 0; k < 8; ++k) {
            fa0[k] = (float)qa0[k]; fa1[k] = (float)qa1[k];
            fb0[k] = (float)qb0[k]; fb1[k] = (float)qb1[k];
        }
        float sa, sb_;
        {
            float p0 = fa0[0]*c0a.x + fa0[1]*c0a.y + fa0[2]*c0a.z + fa0[3]*c0a.w;
            float p1 = fa0[4]*c0b.x + fa0[5]*c0b.y + fa0[6]*c0b.z + fa0[7]*c0b.w;
            float p2 = fa1[0]*c1a.x + fa1[1]*c1a.y + fa1[2]*c1a.z + fa1[3]*c1a.w;
            float p3 = fa1[4]*c1b.x + fa1[5]*c1b.y + fa1[6]*c1b.z + fa1[7]*c1b.w;
            sa = (p0 + p1) + (p2 + p3);
        }
        {
            float p0 = fb0[0]*c0a.x + fb0[1]*c0a.y + fb0[2]*c0a.z + fb0[3]*c0a.w;
            float p1 = fb0[4]*c0b.x + fb0[5]*c0b.y + fb0[6]*c0b.z + fb0[7]*c0b.w;
            float p2 = fb1[0]*c1a.x + fb1[1]*c1a.y + fb1[2]*c1a.z + fb1[3]*c1a.w;
            float p3 = fb1[4]*c1b.x + fb1[5]*c1b.y + fb1[6]*c1b.z + fb1[7]*c1b.w;
            sb_ = (p0 + p1) + (p2 + p3);
        }
#pragma unroll
        for (int o = 32; o > 0; o >>= 1) {     // two interleaved butterflies
            float ta = __shfl_xor(sa, o, 64);
            float tb = __shfl_xor(sb_, o, 64);
            sa += ta; sb_ += tb;
        }
        float ra = 1.0f / sa;
        float rb = hasB ? (1.0f / sb_) : 0.f;  // dup row contributes nothing
#pragma unroll
        for (int k = 0; k < 8; ++k) {
            acc0[k] += fa0[k] * ra + fb0[k] * rb;
            acc1[k] += fa1[k] * ra + fb1[k] * rb;
        }
    }
    *(float4*)&mg[w][col0]           = make_float4(acc0[0], acc0[1], acc0[2], acc0[3]);
    *(float4*)&mg[w][col0 + 4]       = make_float4(acc0[4], acc0[5], acc0[6], acc0[7]);
    *(float4*)&mg[w][512 + col0]     = make_float4(acc1[0], acc1[1], acc1[2], acc1[3]);
    *(float4*)&mg[w][512 + col0 + 4] = make_float4(acc1[4], acc1[5], acc1[6], acc1[7]);
    __syncthreads();
    int j = t << 2;
    float4 m = make_float4(0.f, 0.f, 0.f, 0.f);
#pragma unroll
    for (int ww = 0; ww < 4; ++ww) {
        float4 v = *(const float4*)&mg[ww][j];
        m.x += v.x; m.y += v.y; m.z += v.z; m.w += v.w;
    }
    *(float4*)(pout + (((size_t)((chunk << 6) + b)) << 10) + j) = m;
}

// ---------------------------------------------------------------------------
// K3: fused c5-reduce + 5th col/row-normalize + output write. grid (16, B),
// block 256 -- same shape as pair_k (replaces the old 65536-block finalize +
// separate reduce_c kernel). Stages c5 = 1/colsum (masked) into LDS once per
// block, then each wave holds full rows in registers, reduces with a 64-lane
// butterfly only (NO block barriers in the row loop), and streams float4
// stores. Rows >= nr write zeros without loading A. Two rows in flight for
// shuffle-latency hiding.
// ---------------------------------------------------------------------------
__global__ __launch_bounds__(256) void finalize2_k(
    const _Float16* __restrict__ A, const float* __restrict__ pin,
    const int* __restrict__ nrows, const int* __restrict__ ncols,
    float* __restrict__ out)
{
    __shared__ float cs[NN];        // 4 KB
    int chunk = blockIdx.x, b = blockIdx.y;
    int nr = nrows[b], nc = ncols[b];
    int t = threadIdx.x;
    {
        int j = t << 2;
        const float* pb = pin + ((size_t)b << 10) + j;
        float4 u = make_float4(0.f, 0.f, 0.f, 0.f);
#pragma unroll
        for (int k = 0; k < 16; ++k) {
            float4 p = *(const float4*)(pb + ((size_t)k << 16));
            u.x += p.x; u.y += p.y; u.z += p.z; u.w += p.w;
        }
        cs[j + 0] = (j + 0 < nc) ? 1.0f / u.x : 0.f;
        cs[j + 1] = (j + 1 < nc) ? 1.0f / u.y : 0.f;
        cs[j + 2] = (j + 2 < nc) ? 1.0f / u.z : 0.f;
        cs[j + 3] = (j + 3 < nc) ? 1.0f / u.w : 0.f;
    }
    __syncthreads();

    int w = t >> 6, lane = t & 63;
    int col0 = lane << 3;
    float4 c0a = *(const float4*)&cs[col0];
    float4 c0b = *(const float4*)&cs[col0 + 4];
    float4 c1a = *(const float4*)&cs[512 + col0];
    float4 c1b = *(const float4*)&cs[512 + col0 + 4];
    bool do1 = (512 + col0) < nc;

    const _Float16* Ab = A + ((size_t)b << 20);
    float* Ob = out + ((size_t)b << 20);
    int i0 = chunk << 6;
    int iend = min(i0 + 64, nr);
    for (int i = i0 + w; i < iend; i += 8) {
        int ib = i + 4;
        bool hasB = ib < iend;
        const _Float16* rA = Ab + ((size_t)i << 10);
        const _Float16* rB = Ab + ((size_t)(hasB ? ib : i) << 10);
        f16x8 qa0 = *(const f16x8*)(rA + col0);
        f16x8 qb0 = *(const f16x8*)(rB + col0);
        f16x8 qa1 = {}; f16x8 qb1 = {};
        if (do1) {
            qa1 = *(const f16x8*)(rA + 512 + col0);
            qb1 = *(const f16x8*)(rB + 512 + col0);
        }
        // p = A * c5 (exactly what gets row-normalized and stored)
        float pa[16], pb2[16];
        pa[0]  = (float)qa0[0]*c0a.x; pa[1]  = (float)qa0[1]*c0a.y;
        pa[2]  = (float)qa0[2]*c0a.z; pa[3]  = (float)qa0[3]*c0a.w;
        pa[4]  = (float)qa0[4]*c0b.x; pa[5]  = (float)qa0[5]*c0b.y;
        pa[6]  = (float)qa0[6]*c0b.z; pa[7]  = (float)qa0[7]*c0b.w;
        pa[8]  = (float)qa1[0]*c1a.x; pa[9]  = (float)qa1[1]*c1a.y;
        pa[10] = (float)qa1[2]*c1a.z; pa[11] = (float)qa1[3]*c1a.w;
        pa[12] = (float)qa1[4]*c1b.x; pa[13] = (float)qa1[5]*c1b.y;
        pa[14] = (float)qa1[6]*c1b.z; pa[15] = (float)qa1[7]*c1b.w;
        pb2[0]  = (float)qb0[0]*c0a.x; pb2[1]  = (float)qb0[1]*c0a.y;
        pb2[2]  = (float)qb0[2]*c0a.z; pb2[3]  = (float)qb0[3]*c0a.w;
        pb2[4]  = (float)qb0[4]*c0b.x; pb2[5]  = (float)qb0[5]*c0b.y;
        pb2[6]  = (float)qb0[6]*c0b.z; pb2[7]  = (float)qb0[7]*c0b.w;
        pb2[8]  = (float)qb1[0]*c1a.x; pb2[9]  = (float)qb1[1]*c1a.y;
        pb2[10] = (float)qb1[2]*c1a.z; pb2[11] = (float)qb1[3]*c1a.w;
        pb2[12] = (float)qb1[4]*c1b.x; pb2[13] = (float)qb1[5]*c1b.y;
        pb2[14] = (float)qb1[6]*c1b.z; pb2[15] = (float)qb1[7]*c1b.w;
        float sa, sb_;
        {
            float q0 = ((pa[0]+pa[1])+(pa[2]+pa[3])) + ((pa[4]+pa[5])+(pa[6]+pa[7]));
            float q1 = ((pa[8]+pa[9])+(pa[10]+pa[11])) + ((pa[12]+pa[13])+(pa[14]+pa[15]));
            sa = q0 + q1;
        }
        {
            float q0 = ((pb2[0]+pb2[1])+(pb2[2]+pb2[3])) + ((pb2[4]+pb2[5])+(pb2[6]+pb2[7]));
            float q1 = ((pb2[8]+pb2[9])+(pb2[10]+pb2[11])) + ((pb2[12]+pb2[13])+(pb2[14]+pb2[15]));
            sb_ = q0 + q1;
        }
#pragma unroll
        for (int o = 32; o > 0; o >>= 1) {
            float ta = __shfl_xor(sa, o, 64);
            float tb = __shfl_xor(sb_, o, 64);
            sa += ta; sb_ += tb;
        }
        float ra = 1.0f / sa;
        {
            float* o = Ob + ((size_t)i << 10);
            *(float4*)(o + col0)           = make_float4(pa[0]*ra,  pa[1]*ra,  pa[2]*ra,  pa[3]*ra);
            *(float4*)(o + col0 + 4)       = make_float4(pa[4]*ra,  pa[5]*ra,  pa[6]*ra,  pa[7]*ra);
            *(float4*)(o + 512 + col0)     = make_float4(pa[8]*ra,  pa[9]*ra,  pa[10]*ra, pa[11]*ra);
            *(float4*)(o + 512 + col0 + 4) = make_float4(pa[12]*ra, pa[13]*ra, pa[14]*ra, pa[15]*ra);
        }
        if (hasB) {
            float rb = 1.0f / sb_;
            float* o = Ob + ((size_t)ib << 10);
            *(float4*)(o + col0)           = make_float4(pb2[0]*rb,  pb2[1]*rb,  pb2[2]*rb,  pb2[3]*rb);
            *(float4*)(o + col0 + 4)       = make_float4(pb2[4]*rb,  pb2[5]*rb,  pb2[6]*rb,  pb2[7]*rb);
            *(float4*)(o + 512 + col0)     = make_float4(pb2[8]*rb,  pb2[9]*rb,  pb2[10]*rb, pb2[11]*rb);
            *(float4*)(o + 512 + col0 + 4) = make_float4(pb2[12]*rb, pb2[13]*rb, pb2[14]*rb, pb2[15]*rb);
        }
    }
    // zero rows >= nr (wave-uniform branch, full-row float4 stores)
    for (int i = i0 + w; i < i0 + 64; i += 4) {
        if (i >= nr) {
            float* o = Ob + ((size_t)i << 10);
            float4 z = make_float4(0.f, 0.f, 0.f, 0.f);
            *(float4*)(o + col0)           = z;
            *(float4*)(o + col0 + 4)       = z;
            *(float4*)(o + 512 + col0)     = z;
            *(float4*)(o + 512 + col0 + 4) = z;
        }
    }
}

extern "C" void kernel_launch(void* const* d_in, const int* in_sizes, int n_in,
                              void* d_out, int out_size, void* d_ws, size_t ws_size,
                              hipStream_t stream) {
    const float* s     = (const float*)d_in[0];
    // d_in[1] = n1, d_in[2] = n2 (static 1024, unused)
    const int*   nrows = (const int*)d_in[3];
    const int*   ncols = (const int*)d_in[4];
    float* out = (float*)d_out;

    // ws layout: A (fp16, 134.2 MB) | partialA (4 MB) | partialB (4 MB)
    _Float16* A  = (_Float16*)d_ws;
    float* pA    = (float*)((char*)d_ws + ((size_t)BB << 20) * sizeof(_Float16));
    float* pB    = pA + ((size_t)16 * BB * NN);

    // 10 Sinkhorn iterations = 5 col-normalizes (c1..c5) + 5 row-normalizes
    // (r1..r5) as cumulative scale-vector updates. r1..r4 live only inside
    // pair_k; c5-reduce + r5 are fused into finalize2.
    compress_colsum_k<<<dim3(16, BB), 256, 0, stream>>>(s, A, nrows, ncols, pA);
    pair_k<<<dim3(16, BB), 256, 0, stream>>>(A, pA, nrows, ncols, pB); // c1 -> c2 partial
    pair_k<<<dim3(16, BB), 256, 0, stream>>>(A, pB, nrows, ncols, pA); // c2 -> c3
    pair_k<<<dim3(16, BB), 256, 0, stream>>>(A, pA, nrows, ncols, pB); // c3 -> c4
    pair_k<<<dim3(16, BB), 256, 0, stream>>>(A, pB, nrows, ncols, pA); // c4 -> c5
    finalize2_k<<<dim3(16, BB), 256, 0, stream>>>(A, pA, nrows, ncols, out); // c5,r5 -> out
}